// Round 5
// baseline (447.180 us; speedup 1.0000x reference)
//
#include <hip/hip_runtime.h>

#define NPTS 131072
#define NCEN 128

// Mahalanobis quadratic form, numpy-order (mul then add, explicit _rn ops: no
// fma contraction, stays close to the np reference bit-for-bit).
// C layout per center: inv_cov A[9] row-major, then center xyz at [9..11].
__device__ __forceinline__ float qeval(const float* C,
                                       float px, float py, float pz) {
    float dx = __fsub_rn(px, C[9]);
    float dy = __fsub_rn(py, C[10]);
    float dz = __fsub_rn(pz, C[11]);
    float t0 = __fadd_rn(__fadd_rn(__fmul_rn(dx, C[0]), __fmul_rn(dy, C[3])), __fmul_rn(dz, C[6]));
    float t1 = __fadd_rn(__fadd_rn(__fmul_rn(dx, C[1]), __fmul_rn(dy, C[4])), __fmul_rn(dz, C[7]));
    float t2 = __fadd_rn(__fadd_rn(__fmul_rn(dx, C[2]), __fmul_rn(dy, C[5])), __fmul_rn(dz, C[8]));
    return __fadd_rn(__fadd_rn(__fmul_rn(t0, dx), __fmul_rn(t1, dy)), __fmul_rn(t2, dz));
}

// ---------- kernel 1: zero accumulators + per-center inv_cov + bbox pen ----------
__global__ void k_precompute(const float* __restrict__ centers,
                             const float* __restrict__ radii,
                             const float* __restrict__ rots,
                             float* __restrict__ ws) {
    int n = threadIdx.x;
    if (n < 2) ws[NCEN * 12 + n] = 0.f;   // pen accum, bbox accum
    __syncthreads();                      // single block: safe ordering vs atomics
    if (n >= NCEN) return;
    float c0 = centers[3 * n + 0];
    float c1 = centers[3 * n + 1];
    float c2 = centers[3 * n + 2];
    float d0 = 1.0f / (fabsf(radii[3 * n + 0]) + 1e-8f);
    float d1 = 1.0f / (fabsf(radii[3 * n + 1]) + 1e-8f);
    float d2 = 1.0f / (fabsf(radii[3 * n + 2]) + 1e-8f);
    float a0 = rots[3 * n + 0];
    float a1 = rots[3 * n + 1];
    float a2 = rots[3 * n + 2];
    float cx = cosf(a0), cy = cosf(a1), cz = cosf(a2);
    float sx = sinf(a0), sy = sinf(a1), sz = sinf(a2);
    float R[9];
    R[0] = __fmul_rn(cz, cy);
    R[1] = __fsub_rn(__fmul_rn(__fmul_rn(cz, sy), sx), __fmul_rn(sz, cx));
    R[2] = __fadd_rn(__fmul_rn(__fmul_rn(cz, sy), cx), __fmul_rn(sz, sx));
    R[3] = __fmul_rn(sz, cy);
    R[4] = __fadd_rn(__fmul_rn(__fmul_rn(sz, sy), sx), __fmul_rn(cz, cx));
    R[5] = __fsub_rn(__fmul_rn(__fmul_rn(sz, sy), cx), __fmul_rn(cz, sx));
    R[6] = -sy;
    R[7] = __fmul_rn(cy, sx);
    R[8] = __fmul_rn(cy, cx);
    float T[9];
    T[0] = __fmul_rn(R[0], d0); T[1] = __fmul_rn(R[1], d1); T[2] = __fmul_rn(R[2], d2);
    T[3] = __fmul_rn(R[3], d0); T[4] = __fmul_rn(R[4], d1); T[5] = __fmul_rn(R[5], d2);
    T[6] = __fmul_rn(R[6], d0); T[7] = __fmul_rn(R[7], d1); T[8] = __fmul_rn(R[8], d2);
    float* W = ws + n * 12;
#pragma unroll
    for (int a = 0; a < 3; ++a)
#pragma unroll
        for (int c = 0; c < 3; ++c)
            W[3 * a + c] = __fadd_rn(__fadd_rn(__fmul_rn(T[3 * a + 0], R[3 * c + 0]),
                                               __fmul_rn(T[3 * a + 1], R[3 * c + 1])),
                                     __fmul_rn(T[3 * a + 2], R[3 * c + 2]));
    W[9] = c0; W[10] = c1; W[11] = c2;
    float bb = fmaxf(c0 - 0.5f, 0.f) + fmaxf(-0.5f - c0, 0.f)
             + fmaxf(c1 - 0.5f, 0.f) + fmaxf(-0.5f - c1, 0.f)
             + fmaxf(c2 - 0.5f, 0.f) + fmaxf(-0.5f - c2, 0.f);
    atomicAdd(ws + NCEN * 12 + 1, bb);
}

// ---------- kernel 2: 2 threads/point; w cached in regs; STREAMED rgbs ----------
// R3 post-mortem: gathering only selected entries ran at ~465 GB/s (random 64B
// lines at 2MB stride) -> 165us. Streaming ALL of rgbs coalesced (268MB) at
// ~6TB/s is ~3x faster despite 3.5x the bytes. Loads are unconditional; only
// the FMA accumulation is predicated (w[j] >= cut).
// Selection in w-space: top-16 largest w per thread (descending insert network).
// Two-lane merge identity (DESCENDING arrays): 16th largest of union =
//   min_{i+j=15} max(a[i], b[j])           <- R4 bug: had max-of-min (ascending form)
// Exact w>=0.01 threshold folded into cut. Pen is branchless-exact over all centers.
__global__ __launch_bounds__(256, 4) void k_main(
        const float* __restrict__ wxyz,
        const float* __restrict__ dists,
        const float4* __restrict__ rgbs,
        const float* __restrict__ ws,
        float2* __restrict__ outv,
        float* __restrict__ pen_out) {
    __shared__ float sws[NCEN * 12];
    int tid = threadIdx.x;
#pragma unroll
    for (int i = tid; i < NCEN * 12; i += 256) sws[i] = ws[i];
    __syncthreads();

    int gid = blockIdx.x * 256 + tid;
    int p = gid >> 1;          // point index
    int slice = gid & 1;       // center slice: n = 2j + slice
    float px = wxyz[3 * p + 0];
    float py = wxyz[3 * p + 1];
    float pz = wxyz[3 * p + 2];
    float dist = dists[p];

    float w[64];
    float top[16];             // 16 largest w, descending
#pragma unroll
    for (int i = 0; i < 16; ++i) top[i] = -1.0f;
    float pen = 0.f;

    // pass 1: w for my 64 centers (cached in regs), pen, descending top-16 insert
#pragma unroll
    for (int j = 0; j < 64; ++j) {
        int n = 2 * j + slice;
        float qq = qeval(&sws[n * 12], px, py, pz);
        float wv = __fmul_rn(5.0f, expf(__fmul_rn(-0.5f, qq)));
        w[j] = wv;
        pen = __fadd_rn(pen, fmaxf(__fsub_rn(wv, 0.01f), 0.f));
#pragma unroll
        for (int k = 15; k >= 1; --k)
            top[k] = fmaxf(top[k], fminf(wv, top[k - 1]));
        top[0] = fmaxf(top[0], wv);
    }

    // merge across the 2 lanes of this point: 16th largest of union (min of max)
    float wcut = 3.0e38f;
#pragma unroll
    for (int i = 0; i < 16; ++i) {
        float b = __shfl_xor(top[15 - i], 1);
        wcut = fminf(wcut, fmaxf(top[i], b));
    }
    float cut = fmaxf(wcut, 0.01f);

    // pass 2: stream my 64 rgbs rows (coalesced, unconditional), predicated blend
    float wsum = 0.f, s0 = 0.f, s1 = 0.f, s2 = 0.f, s3 = 0.f;
#pragma unroll 8
    for (int j = 0; j < 64; ++j) {
        int n = 2 * j + slice;
        float4 rv = rgbs[(size_t)n * NPTS + p];
        if (w[j] >= cut) {
            float al = __fsub_rn(1.0f, expf(-__fmul_rn(fmaxf(rv.w, 0.f), dist)));
            wsum += w[j];
            s0 = __fmaf_rn(w[j], rv.x, s0);
            s1 = __fmaf_rn(w[j], rv.y, s1);
            s2 = __fmaf_rn(w[j], rv.z, s2);
            s3 = __fmaf_rn(w[j], al, s3);
        }
    }
    // allreduce blend partials across the 2 lanes of this point
    wsum += __shfl_xor(wsum, 1);
    s0   += __shfl_xor(s0, 1);
    s1   += __shfl_xor(s1, 1);
    s2   += __shfl_xor(s2, 1);
    s3   += __shfl_xor(s3, 1);
    float inv = 1.0f / (wsum + 1e-7f);
    float2 o;
    o.x = (slice ? s2 : s0) * inv;
    o.y = (slice ? s3 : s1) * inv;
    outv[gid] = o;             // element (p*4 + 2*slice + {0,1}): fully coalesced

    // penalty reduction: wave shuffle, one atomic per wave
    float v = pen;
#pragma unroll
    for (int off = 32; off > 0; off >>= 1) v += __shfl_down(v, off);
    if ((tid & 63) == 0) atomicAdd(pen_out, v);
}

// ---------- kernel 3: finalize scalar penalty ----------
__global__ void k_finalize(const float* __restrict__ ws,
                           float* __restrict__ out) {
    if (threadIdx.x == 0) {
        float m = ws[NCEN * 12] / (float)NPTS;       // mean over points
        out[NPTS * 4] = __fadd_rn(__fmul_rn(0.001f, m), ws[NCEN * 12 + 1]);
    }
}

extern "C" void kernel_launch(void* const* d_in, const int* in_sizes, int n_in,
                              void* d_out, int out_size, void* d_ws, size_t ws_size,
                              hipStream_t stream) {
    const float*  wxyz  = (const float*)d_in[0];
    const float*  cen   = (const float*)d_in[1];
    const float*  rad   = (const float*)d_in[2];
    const float*  rot   = (const float*)d_in[3];
    const float4* rgbs  = (const float4*)d_in[4];
    const float*  dists = (const float*)d_in[5];
    float* ws = (float*)d_ws;

    hipLaunchKernelGGL(k_precompute, dim3(1), dim3(128), 0, stream, cen, rad, rot, ws);
    hipLaunchKernelGGL(k_main, dim3(2 * NPTS / 256), dim3(256), 0, stream,
                       wxyz, dists, rgbs, ws, (float2*)d_out, ws + NCEN * 12);
    hipLaunchKernelGGL(k_finalize, dim3(1), dim3(64), 0, stream, ws, (float*)d_out);
}

// Round 6
// 422.108 us; speedup vs baseline: 1.0594x; 1.0594x over previous
//
#include <hip/hip_runtime.h>

#define NPTS 131072
#define NCEN 128

// Mahalanobis quadratic form, numpy-order (mul then add, explicit _rn ops: no
// fma contraction, stays close to the np reference bit-for-bit).
// C layout per center: inv_cov A[9] row-major, then center xyz at [9..11].
__device__ __forceinline__ float qeval(const float* C,
                                       float px, float py, float pz) {
    float dx = __fsub_rn(px, C[9]);
    float dy = __fsub_rn(py, C[10]);
    float dz = __fsub_rn(pz, C[11]);
    float t0 = __fadd_rn(__fadd_rn(__fmul_rn(dx, C[0]), __fmul_rn(dy, C[3])), __fmul_rn(dz, C[6]));
    float t1 = __fadd_rn(__fadd_rn(__fmul_rn(dx, C[1]), __fmul_rn(dy, C[4])), __fmul_rn(dz, C[7]));
    float t2 = __fadd_rn(__fadd_rn(__fmul_rn(dx, C[2]), __fmul_rn(dy, C[5])), __fmul_rn(dz, C[8]));
    return __fadd_rn(__fadd_rn(__fmul_rn(t0, dx), __fmul_rn(t1, dy)), __fmul_rn(t2, dz));
}

// ---------- kernel 1: zero accumulators + per-center inv_cov + bbox pen ----------
__global__ void k_precompute(const float* __restrict__ centers,
                             const float* __restrict__ radii,
                             const float* __restrict__ rots,
                             float* __restrict__ ws) {
    int n = threadIdx.x;
    if (n < 2) ws[NCEN * 12 + n] = 0.f;   // pen accum, bbox accum
    __syncthreads();                      // single block: safe ordering vs atomics
    if (n >= NCEN) return;
    float c0 = centers[3 * n + 0];
    float c1 = centers[3 * n + 1];
    float c2 = centers[3 * n + 2];
    float d0 = 1.0f / (fabsf(radii[3 * n + 0]) + 1e-8f);
    float d1 = 1.0f / (fabsf(radii[3 * n + 1]) + 1e-8f);
    float d2 = 1.0f / (fabsf(radii[3 * n + 2]) + 1e-8f);
    float a0 = rots[3 * n + 0];
    float a1 = rots[3 * n + 1];
    float a2 = rots[3 * n + 2];
    float cx = cosf(a0), cy = cosf(a1), cz = cosf(a2);
    float sx = sinf(a0), sy = sinf(a1), sz = sinf(a2);
    float R[9];
    R[0] = __fmul_rn(cz, cy);
    R[1] = __fsub_rn(__fmul_rn(__fmul_rn(cz, sy), sx), __fmul_rn(sz, cx));
    R[2] = __fadd_rn(__fmul_rn(__fmul_rn(cz, sy), cx), __fmul_rn(sz, sx));
    R[3] = __fmul_rn(sz, cy);
    R[4] = __fadd_rn(__fmul_rn(__fmul_rn(sz, sy), sx), __fmul_rn(cz, cx));
    R[5] = __fsub_rn(__fmul_rn(__fmul_rn(sz, sy), cx), __fmul_rn(cz, sx));
    R[6] = -sy;
    R[7] = __fmul_rn(cy, sx);
    R[8] = __fmul_rn(cy, cx);
    float T[9];
    T[0] = __fmul_rn(R[0], d0); T[1] = __fmul_rn(R[1], d1); T[2] = __fmul_rn(R[2], d2);
    T[3] = __fmul_rn(R[3], d0); T[4] = __fmul_rn(R[4], d1); T[5] = __fmul_rn(R[5], d2);
    T[6] = __fmul_rn(R[6], d0); T[7] = __fmul_rn(R[7], d1); T[8] = __fmul_rn(R[8], d2);
    float* W = ws + n * 12;
#pragma unroll
    for (int a = 0; a < 3; ++a)
#pragma unroll
        for (int c = 0; c < 3; ++c)
            W[3 * a + c] = __fadd_rn(__fadd_rn(__fmul_rn(T[3 * a + 0], R[3 * c + 0]),
                                               __fmul_rn(T[3 * a + 1], R[3 * c + 1])),
                                     __fmul_rn(T[3 * a + 2], R[3 * c + 2]));
    W[9] = c0; W[10] = c1; W[11] = c2;
    float bb = fmaxf(c0 - 0.5f, 0.f) + fmaxf(-0.5f - c0, 0.f)
             + fmaxf(c1 - 0.5f, 0.f) + fmaxf(-0.5f - c1, 0.f)
             + fmaxf(c2 - 0.5f, 0.f) + fmaxf(-0.5f - c2, 0.f);
    atomicAdd(ws + NCEN * 12 + 1, bb);
}

// ---------- kernel 2: 4 threads/point; branchless streamed blend ----------
// R5 post-mortem: (a) load-inside-branch let the compiler sink the stream back
// into a gather (FETCH 110MB, 465GB/s-class); (b) w[64] spilled to scratch
// (WRITE_SIZE 67MB == 256B/thread). Fixes: 4 threads/point -> w[32] fits in
// VGPRs; blend made BRANCHLESS (m = w>=cut ? w : 0, FMAs always execute) so rv
// is unconditionally used and the rgbs stream cannot be sunk. m=0 contributes
// exactly 0 -> numerics identical.
// Cut selection (w-space, descending): per-thread top-16 insert network;
// stage 1 (lanes xor 1): exact merge top-16 = bitonic max(a[i],b[15-i]) + 4-level
// descending cleanup; stage 2 (lanes xor 2): 16th largest of two descending
// arrays = min_{i+j=15} max(m[i], m'[j]). cut = max(that, 0.01) folds the exact
// w>=0.01 threshold. Pen is branchless-exact over all centers.
__global__ __launch_bounds__(256, 4) void k_main(
        const float* __restrict__ wxyz,
        const float* __restrict__ dists,
        const float4* __restrict__ rgbs,
        const float* __restrict__ ws,
        float* __restrict__ out,
        float* __restrict__ pen_out) {
    __shared__ float sws[NCEN * 12];
    int tid = threadIdx.x;
#pragma unroll
    for (int i = tid; i < NCEN * 12; i += 256) sws[i] = ws[i];
    __syncthreads();

    int gid = blockIdx.x * 256 + tid;
    int p = gid >> 2;          // point index
    int slice = gid & 3;       // center slice: n = 4j + slice
    float px = wxyz[3 * p + 0];
    float py = wxyz[3 * p + 1];
    float pz = wxyz[3 * p + 2];
    float dist = dists[p];

    float w[32];
    float top[16];             // 16 largest w, descending
#pragma unroll
    for (int i = 0; i < 16; ++i) top[i] = -1.0f;
    float pen = 0.f;

    // pass 1: w for my 32 centers (cached in regs), pen, descending top-16 insert
#pragma unroll
    for (int j = 0; j < 32; ++j) {
        int n = 4 * j + slice;
        float qq = qeval(&sws[n * 12], px, py, pz);
        float wv = __fmul_rn(5.0f, expf(__fmul_rn(-0.5f, qq)));
        w[j] = wv;
        pen = __fadd_rn(pen, fmaxf(__fsub_rn(wv, 0.01f), 0.f));
#pragma unroll
        for (int k = 15; k >= 1; --k)
            top[k] = fmaxf(top[k], fminf(wv, top[k - 1]));
        top[0] = fmaxf(top[0], wv);
    }

    // stage 1 (lanes xor 1): exact descending merge-top-16
    float m[16];
#pragma unroll
    for (int i = 0; i < 16; ++i) {
        float b = __shfl_xor(top[15 - i], 1);
        m[i] = fmaxf(top[i], b);       // bitonic: contains top-16 of union
    }
#pragma unroll
    for (int d = 8; d >= 1; d >>= 1) {
#pragma unroll
        for (int i = 0; i < 16; ++i) {
            if ((i & d) == 0) {
                float hi = fmaxf(m[i], m[i + d]);
                float lo = fminf(m[i], m[i + d]);
                m[i] = hi; m[i + d] = lo;   // descending cleanup
            }
        }
    }
    // stage 2 (lanes xor 2): 16th largest of union = min of pairwise max
    float wcut = 3.0e38f;
#pragma unroll
    for (int i = 0; i < 16; ++i) {
        float b = __shfl_xor(m[15 - i], 2);
        wcut = fminf(wcut, fmaxf(m[i], b));
    }
    float cut = fmaxf(wcut, 0.01f);

    // pass 2: stream my 32 rgbs rows (coalesced, UNCONDITIONAL use), branchless blend
    float wsum = 0.f, s0 = 0.f, s1 = 0.f, s2 = 0.f, s3 = 0.f;
#pragma unroll 4
    for (int j = 0; j < 32; ++j) {
        int n = 4 * j + slice;
        float4 rv = rgbs[(size_t)n * NPTS + p];
        float mw = (w[j] >= cut) ? w[j] : 0.0f;
        float al = __fsub_rn(1.0f, expf(-__fmul_rn(fmaxf(rv.w, 0.f), dist)));
        wsum += mw;
        s0 = __fmaf_rn(mw, rv.x, s0);
        s1 = __fmaf_rn(mw, rv.y, s1);
        s2 = __fmaf_rn(mw, rv.z, s2);
        s3 = __fmaf_rn(mw, al, s3);
    }
    // allreduce blend partials across the 4 lanes of this point
#pragma unroll
    for (int off = 1; off <= 2; off <<= 1) {
        wsum += __shfl_xor(wsum, off);
        s0   += __shfl_xor(s0, off);
        s1   += __shfl_xor(s1, off);
        s2   += __shfl_xor(s2, off);
        s3   += __shfl_xor(s3, off);
    }
    float inv = 1.0f / (wsum + 1e-7f);
    float val = (slice == 0) ? s0 : (slice == 1) ? s1 : (slice == 2) ? s2 : s3;
    out[gid] = val * inv;   // gid == p*4 + slice: fully coalesced

    // penalty reduction: wave shuffle, one atomic per wave
    float v = pen;
#pragma unroll
    for (int off = 32; off > 0; off >>= 1) v += __shfl_down(v, off);
    if ((tid & 63) == 0) atomicAdd(pen_out, v);
}

// ---------- kernel 3: finalize scalar penalty ----------
__global__ void k_finalize(const float* __restrict__ ws,
                           float* __restrict__ out) {
    if (threadIdx.x == 0) {
        float m = ws[NCEN * 12] / (float)NPTS;       // mean over points
        out[NPTS * 4] = __fadd_rn(__fmul_rn(0.001f, m), ws[NCEN * 12 + 1]);
    }
}

extern "C" void kernel_launch(void* const* d_in, const int* in_sizes, int n_in,
                              void* d_out, int out_size, void* d_ws, size_t ws_size,
                              hipStream_t stream) {
    const float*  wxyz  = (const float*)d_in[0];
    const float*  cen   = (const float*)d_in[1];
    const float*  rad   = (const float*)d_in[2];
    const float*  rot   = (const float*)d_in[3];
    const float4* rgbs  = (const float4*)d_in[4];
    const float*  dists = (const float*)d_in[5];
    float* ws = (float*)d_ws;

    hipLaunchKernelGGL(k_precompute, dim3(1), dim3(128), 0, stream, cen, rad, rot, ws);
    hipLaunchKernelGGL(k_main, dim3(4 * NPTS / 256), dim3(256), 0, stream,
                       wxyz, dists, rgbs, ws, (float*)d_out, ws + NCEN * 12);
    hipLaunchKernelGGL(k_finalize, dim3(1), dim3(64), 0, stream, ws, (float*)d_out);
}

// Round 7
// 403.190 us; speedup vs baseline: 1.1091x; 1.0469x over previous
//
#include <hip/hip_runtime.h>

#define NPTS 131072
#define NCEN 128

// Mahalanobis quadratic form, numpy-order (mul then add, explicit _rn ops: no
// fma contraction). Called twice per (point,center); inputs come from the same
// LDS copy both times -> bit-identical results, so pass-2 recompute reproduces
// pass-1 selection exactly.
__device__ __forceinline__ float qeval(const float* C,
                                       float px, float py, float pz) {
    float dx = __fsub_rn(px, C[9]);
    float dy = __fsub_rn(py, C[10]);
    float dz = __fsub_rn(pz, C[11]);
    float t0 = __fadd_rn(__fadd_rn(__fmul_rn(dx, C[0]), __fmul_rn(dy, C[3])), __fmul_rn(dz, C[6]));
    float t1 = __fadd_rn(__fadd_rn(__fmul_rn(dx, C[1]), __fmul_rn(dy, C[4])), __fmul_rn(dz, C[7]));
    float t2 = __fadd_rn(__fadd_rn(__fmul_rn(dx, C[2]), __fmul_rn(dy, C[5])), __fmul_rn(dz, C[8]));
    return __fadd_rn(__fadd_rn(__fmul_rn(t0, dx), __fmul_rn(t1, dy)), __fmul_rn(t2, dz));
}

// ---------- kernel 1: zero accumulators + per-center inv_cov + bbox pen ----------
__global__ void k_precompute(const float* __restrict__ centers,
                             const float* __restrict__ radii,
                             const float* __restrict__ rots,
                             float* __restrict__ ws) {
    int n = threadIdx.x;
    if (n < 2) ws[NCEN * 12 + n] = 0.f;   // pen accum, bbox accum
    __syncthreads();                      // single block: safe ordering vs atomics
    if (n >= NCEN) return;
    float c0 = centers[3 * n + 0];
    float c1 = centers[3 * n + 1];
    float c2 = centers[3 * n + 2];
    float d0 = 1.0f / (fabsf(radii[3 * n + 0]) + 1e-8f);
    float d1 = 1.0f / (fabsf(radii[3 * n + 1]) + 1e-8f);
    float d2 = 1.0f / (fabsf(radii[3 * n + 2]) + 1e-8f);
    float a0 = rots[3 * n + 0];
    float a1 = rots[3 * n + 1];
    float a2 = rots[3 * n + 2];
    float cx = cosf(a0), cy = cosf(a1), cz = cosf(a2);
    float sx = sinf(a0), sy = sinf(a1), sz = sinf(a2);
    float R[9];
    R[0] = __fmul_rn(cz, cy);
    R[1] = __fsub_rn(__fmul_rn(__fmul_rn(cz, sy), sx), __fmul_rn(sz, cx));
    R[2] = __fadd_rn(__fmul_rn(__fmul_rn(cz, sy), cx), __fmul_rn(sz, sx));
    R[3] = __fmul_rn(sz, cy);
    R[4] = __fadd_rn(__fmul_rn(__fmul_rn(sz, sy), sx), __fmul_rn(cz, cx));
    R[5] = __fsub_rn(__fmul_rn(__fmul_rn(sz, sy), cx), __fmul_rn(cz, sx));
    R[6] = -sy;
    R[7] = __fmul_rn(cy, sx);
    R[8] = __fmul_rn(cy, cx);
    float T[9];
    T[0] = __fmul_rn(R[0], d0); T[1] = __fmul_rn(R[1], d1); T[2] = __fmul_rn(R[2], d2);
    T[3] = __fmul_rn(R[3], d0); T[4] = __fmul_rn(R[4], d1); T[5] = __fmul_rn(R[5], d2);
    T[6] = __fmul_rn(R[6], d0); T[7] = __fmul_rn(R[7], d1); T[8] = __fmul_rn(R[8], d2);
    float* W = ws + n * 12;
#pragma unroll
    for (int a = 0; a < 3; ++a)
#pragma unroll
        for (int c = 0; c < 3; ++c)
            W[3 * a + c] = __fadd_rn(__fadd_rn(__fmul_rn(T[3 * a + 0], R[3 * c + 0]),
                                               __fmul_rn(T[3 * a + 1], R[3 * c + 1])),
                                     __fmul_rn(T[3 * a + 2], R[3 * c + 2]));
    W[9] = c0; W[10] = c1; W[11] = c2;
    float bb = fmaxf(c0 - 0.5f, 0.f) + fmaxf(-0.5f - c0, 0.f)
             + fmaxf(c1 - 0.5f, 0.f) + fmaxf(-0.5f - c1, 0.f)
             + fmaxf(c2 - 0.5f, 0.f) + fmaxf(-0.5f - c2, 0.f);
    atomicAdd(ws + NCEN * 12 + 1, bb);
}

// ---------- kernel 2: 1 thread/point; pass-2 recompute; contiguous 1KB/wave stream ----------
// R6 post-mortem: 4 threads/point made each wave-load 4 disjoint 256B runs 2MB
// apart -> stream ran at ~1.9 TB/s (vs 6.8 TB/s for the harness's linear fill).
// This version: 1 thread/point, so each rgbs load instruction covers 64
// consecutive points x 16B = one contiguous 1KB run (fill-like shape).
// No w[] cache (that's what forced 4 threads/point): pass 2 recomputes q/w
// bit-identically from the same LDS table. Selection is purely per-thread:
// ascending-q insert network over all 128 centers, qcut = top[15] = 16th
// smallest q; blend mask = (q <= qcut) && (w >= 0.01) -- exact reference
// semantics (top-16 in w-space == bottom-16 in q-space; threshold exact).
// Pen guard q <= 13 is exact: w(13) = 0.0075 < 0.01 -> relu term is 0 there.
// Loads stay unconditional (mask only zeroes the FMA multiplier).
__global__ __launch_bounds__(256, 2) void k_main(
        const float* __restrict__ wxyz,
        const float* __restrict__ dists,
        const float4* __restrict__ rgbs,
        const float* __restrict__ ws,
        float4* __restrict__ outv,
        float* __restrict__ pen_out) {
    __shared__ float sws[NCEN * 12];
    int tid = threadIdx.x;
#pragma unroll
    for (int i = tid; i < NCEN * 12; i += 256) sws[i] = ws[i];
    __syncthreads();

    int p = blockIdx.x * 256 + tid;
    float px = wxyz[3 * p + 0];
    float py = wxyz[3 * p + 1];
    float pz = wxyz[3 * p + 2];
    float dist = dists[p];

    float top[16];             // 16 smallest q, ascending
#pragma unroll
    for (int i = 0; i < 16; ++i) top[i] = 3.0e38f;
    float pen = 0.f;

    // pass 1: q over all 128 centers; pen (guarded, exact); top-16 insert
    for (int n = 0; n < NCEN; ++n) {
        float q = qeval(&sws[n * 12], px, py, pz);
        if (q <= 13.0f) {
            float wv = __fmul_rn(5.0f, expf(__fmul_rn(-0.5f, q)));
            pen = __fadd_rn(pen, fmaxf(__fsub_rn(wv, 0.01f), 0.f));
        }
#pragma unroll
        for (int k = 15; k >= 1; --k)
            top[k] = fminf(top[k], fmaxf(q, top[k - 1]));
        top[0] = fminf(top[0], q);
    }
    float qcut = top[15];

    // pass 2: stream all 128 rgbs rows (64 lanes x 16B contiguous per load),
    // recompute q bit-identically, branchless masked blend
    float wsum = 0.f, s0 = 0.f, s1 = 0.f, s2 = 0.f, s3 = 0.f;
#pragma unroll 8
    for (int n = 0; n < NCEN; ++n) {
        float4 rv = rgbs[(size_t)n * NPTS + p];
        float q = qeval(&sws[n * 12], px, py, pz);
        float wv = __fmul_rn(5.0f, expf(__fmul_rn(-0.5f, q)));
        float mw = ((q <= qcut) && (wv >= 0.01f)) ? wv : 0.0f;
        float al = __fsub_rn(1.0f, expf(-__fmul_rn(fmaxf(rv.w, 0.f), dist)));
        wsum += mw;
        s0 = __fmaf_rn(mw, rv.x, s0);
        s1 = __fmaf_rn(mw, rv.y, s1);
        s2 = __fmaf_rn(mw, rv.z, s2);
        s3 = __fmaf_rn(mw, al, s3);
    }
    float inv = 1.0f / (wsum + 1e-7f);
    float4 o;
    o.x = s0 * inv; o.y = s1 * inv; o.z = s2 * inv; o.w = s3 * inv;
    outv[p] = o;               // 16B/lane, fully coalesced

    // penalty reduction: wave shuffle, one atomic per wave
    float v = pen;
#pragma unroll
    for (int off = 32; off > 0; off >>= 1) v += __shfl_down(v, off);
    if ((tid & 63) == 0) atomicAdd(pen_out, v);
}

// ---------- kernel 3: finalize scalar penalty ----------
__global__ void k_finalize(const float* __restrict__ ws,
                           float* __restrict__ out) {
    if (threadIdx.x == 0) {
        float m = ws[NCEN * 12] / (float)NPTS;       // mean over points
        out[NPTS * 4] = __fadd_rn(__fmul_rn(0.001f, m), ws[NCEN * 12 + 1]);
    }
}

extern "C" void kernel_launch(void* const* d_in, const int* in_sizes, int n_in,
                              void* d_out, int out_size, void* d_ws, size_t ws_size,
                              hipStream_t stream) {
    const float*  wxyz  = (const float*)d_in[0];
    const float*  cen   = (const float*)d_in[1];
    const float*  rad   = (const float*)d_in[2];
    const float*  rot   = (const float*)d_in[3];
    const float4* rgbs  = (const float4*)d_in[4];
    const float*  dists = (const float*)d_in[5];
    float* ws = (float*)d_ws;

    hipLaunchKernelGGL(k_precompute, dim3(1), dim3(128), 0, stream, cen, rad, rot, ws);
    hipLaunchKernelGGL(k_main, dim3(NPTS / 256), dim3(256), 0, stream,
                       wxyz, dists, rgbs, ws, (float4*)d_out, ws + NCEN * 12);
    hipLaunchKernelGGL(k_finalize, dim3(1), dim3(64), 0, stream, ws, (float*)d_out);
}